// Round 1
// 116.373 us; speedup vs baseline: 1.0335x; 1.0335x over previous
//
#include <hip/hip_runtime.h>
#include <cstdint>

// CIN chain: B=1024, F0=32, EMB=64, layers 128/128/128.
// cur[b,k,e] = sum_{i,j} x[b,i,e]*h[b,j,e]*W[i*fi+j,k]
//
// R15: OCCUPANCY RESTRUCTURE of cin_fused. R14 counters: MfmaUtil 20%,
// VALUBusy 15%, Occupancy 19% -> latency-bound at 2 blocks/CU (LDS 60KB,
// grid 512). Changes:
//  * K-split -> M-split: each wave owns 32 of 64 hidden rows over full K.
//    Removes the xchg LDS round-trip (16 KB + f16 partial-sum truncation)
//    and the ks==0-only serial epilogues (all waves now build h images).
//  * 1 batch/block, 128 threads (2 waves), grid 2048. LDS 22528 B ->
//    7 blocks/CU = 14 waves/CU (43.75% cap, was 25%). Seven independent
//    barrier domains per CU hide the per-chunk Wt L2 latency.
//  * sgemm A-fragment (x rows) preloaded to registers from a pitch-72 xJ
//    copy -> kills the 16-way-conflict pitch-64 LDS reads.
//  * cin_direct: K-split-2 across wave pairs (grid 512, 8 waves/CU,
//    dependent chains halved, LDS f32x4 combine).
// LDS region lifetimes (per batch):
//   sX  [i*64+e]  whole kernel (kloop x-broadcast only)
//   R_A hT0(p40) -> [B1] -> hJ1(p72)
//   R_B xJ(p72)  -> [B1] -> hT1(p72) -> [B3] -> hJ2(p72)

typedef _Float16 half8  __attribute__((ext_vector_type(8)));
typedef _Float16 half4_ __attribute__((ext_vector_type(4)));
typedef _Float16 half2_ __attribute__((ext_vector_type(2)));
typedef float    f32x4  __attribute__((ext_vector_type(4)));

// Pack W (fan_in,128) f32 -> chunked f16 Wt[c][m][kk] = W[c*32+kk][m].
__global__ void pack_w_all(const float* __restrict__ W0, _Float16* __restrict__ Wt0,
                           const float* __restrict__ W1, _Float16* __restrict__ Wt1,
                           const float* __restrict__ W2, _Float16* __restrict__ Wt2)
{
    __shared__ _Float16 ldsT[128 * 33];
    const int blk = blockIdx.x, t = threadIdx.x;
    const float* W;
    _Float16* Wt;
    int c;
    if (blk < 32)       { W = W0; Wt = Wt0; c = blk; }
    else if (blk < 96)  { W = W1; Wt = Wt1; c = blk - 32; }
    else                { W = W2; Wt = Wt2; c = blk - 96; }

    for (int p = t; p < 32 * 128; p += 256) {
        int kk = p >> 7, m = p & 127;
        ldsT[m * 33 + kk] = (_Float16)W[(size_t)(c * 32 + kk) * 128 + m];
    }
    __syncthreads();
    int m = t >> 1, kk0 = (t & 1) * 16;
    half8 v0, v1;
#pragma unroll
    for (int i = 0; i < 8; ++i) {
        v0[i] = ldsT[m * 33 + kk0 + i];
        v1[i] = ldsT[m * 33 + kk0 + 8 + i];
    }
    *(half8*)(Wt + (size_t)c * 4096 + t * 16)     = v0;
    *(half8*)(Wt + (size_t)c * 4096 + t * 16 + 8) = v1;
}

// Fused hidden+S kernel. Block = 1 batch, 128 thr = 2 waves (M-split ks).
__global__ __launch_bounds__(128, 4)
void cin_fused(const float* __restrict__ x,          // (1024,32,64) f32
               const _Float16* __restrict__ Wt0,
               const _Float16* __restrict__ Wt1,
               const float* __restrict__ bs0,
               const float* __restrict__ bs1,
               _Float16* __restrict__ S0,             // (1024,1024)
               _Float16* __restrict__ S1,             // (1024,2048)
               _Float16* __restrict__ S2)             // (1024,2048)
{
    __shared__ alignas(16) char smem[22528];
    _Float16* sX  = (_Float16*)smem;                   // 4 KB  [i*64+e]
    _Float16* R_A = (_Float16*)(smem + 4096);          // 9216 B
    _Float16* R_B = (_Float16*)(smem + 13312);         // 9216 B

    const int t = threadIdx.x, lane = t & 63, ks = t >> 6;
    const int lr = lane & 15, q = lane >> 4;
    const int b = blockIdx.x;

    // prologue: x -> sX [i][e]; xJ (pitch 72) -> R_B; hT0 (pitch 40) -> R_A
    {
        const float4* xv = (const float4*)(x + (size_t)b * 2048);
#pragma unroll
        for (int s = 0; s < 4; ++s) {
            int p4 = t + s * 128;
            float4 v = xv[p4];
            int idx = p4 * 4, i = idx >> 6, e0 = idx & 63;
            _Float16 h0 = (_Float16)v.x, h1 = (_Float16)v.y;
            _Float16 h2 = (_Float16)v.z, h3 = (_Float16)v.w;
            half4_ pk = {h0, h1, h2, h3};
            *(half4_*)(sX + i * 64 + e0) = pk;
            *(half4_*)(R_B + i * 72 + e0) = pk;
            R_A[(e0 + 0) * 40 + i] = h0;
            R_A[(e0 + 1) * 40 + i] = h1;
            R_A[(e0 + 2) * 40 + i] = h2;
            R_A[(e0 + 3) * 40 + i] = h3;
        }
    }
    __syncthreads();                                   // B0

    // persistent sgemm A-fragment: x rows ks*16+lr, e = q*8 .. (+32)
    const half8 aF0 = *(const half8*)(R_B + (ks * 16 + lr) * 72 + q * 8);
    const half8 aF1 = *(const half8*)(R_B + (ks * 16 + lr) * 72 + q * 8 + 32);

    f32x4 acc[2][4];

    // full-K M-split kloop: this wave owns hidden rows ks*32 .. ks*32+31
    auto kloop = [&](const _Float16* WtL, int nch, int ish,
                     const _Float16* hb, int ph) {
#pragma unroll
        for (int mt = 0; mt < 2; ++mt)
#pragma unroll
            for (int nt = 0; nt < 4; ++nt)
                acc[mt][nt] = f32x4{0.0f, 0.0f, 0.0f, 0.0f};
        const _Float16* aG = WtL + (ks * 32 + lr) * 32 + q * 8;
        const _Float16* hP = hb + lr * ph + q * 8;
        const _Float16* xP = sX + lr;
        half8 afA[2], afB[2], hvA[4], hvB[4];
        _Float16 xsA[4], xsB[4];
        auto pf = [&](half8* af, half8* hv, _Float16* xs, int c) {
            const int i  = c >> ish;
            const int j0 = (c - (i << ish)) << 5;
            const _Float16* ag = aG + (size_t)c * 4096;
            af[0] = *(const half8*)(ag);
            af[1] = *(const half8*)(ag + 512);
#pragma unroll
            for (int nt = 0; nt < 4; ++nt) {
                hv[nt] = *(const half8*)(hP + nt * (ph << 4) + j0);
                xs[nt] = xP[(i << 6) + (nt << 4)];
            }
        };
        auto cp = [&](half8* af, half8* hv, _Float16* xs) {
#pragma unroll
            for (int nt = 0; nt < 4; ++nt) {
                half2_ xv2 = {xs[nt], xs[nt]};
                half8 xv8 = __builtin_shufflevector(xv2, xv2, 0, 1, 0, 1, 0, 1, 0, 1);
                half8 bf = hv[nt] * xv8;
                acc[0][nt] = __builtin_amdgcn_mfma_f32_16x16x32_f16(
                    af[0], bf, acc[0][nt], 0, 0, 0);
                acc[1][nt] = __builtin_amdgcn_mfma_f32_16x16x32_f16(
                    af[1], bf, acc[1][nt], 0, 0, 0);
            }
        };
        pf(afA, hvA, xsA, 0);
        for (int c = 0; c < nch; c += 2) {
            pf(afB, hvB, xsB, c + 1);
            cp(afA, hvA, xsA);
            if (c + 2 < nch) pf(afA, hvA, xsA, c + 2);
            cp(afB, hvB, xsB);
        }
    };

    // S_l[b][i*fi+j] = sum_e x[i,e]*h[j,e]; i-tile = ks, A from registers
    auto sgemm = [&](const _Float16* hJ, int fi, _Float16* Sdst) {
        const int njt = fi >> 4;
        for (int jt = 0; jt < njt; ++jt) {
            f32x4 sa = {0.0f, 0.0f, 0.0f, 0.0f};
            half8 bv0 = *(const half8*)(hJ + (jt * 16 + lr) * 72 + q * 8);
            half8 bv1 = *(const half8*)(hJ + (jt * 16 + lr) * 72 + q * 8 + 32);
            sa = __builtin_amdgcn_mfma_f32_16x16x32_f16(aF0, bv0, sa, 0, 0, 0);
            sa = __builtin_amdgcn_mfma_f32_16x16x32_f16(aF1, bv1, sa, 0, 0, 0);
#pragma unroll
            for (int r = 0; r < 4; ++r)
                Sdst[(size_t)b * (32 * fi) + (ks * 16 + q * 4 + r) * fi
                     + jt * 16 + lr] = (_Float16)sa[r];
        }
    };

    // epilogue: h = cur + bias for this wave's 32 rows -> hJ (and hT)
    auto epi = [&](const float* bs, _Float16* hJ, _Float16* hT, bool wantT) {
#pragma unroll
        for (int mt = 0; mt < 2; ++mt) {
            const int jb = ks * 32 + mt * 16 + q * 4;
            const float b0f = bs[jb + 0], b1f = bs[jb + 1];
            const float b2f = bs[jb + 2], b3f = bs[jb + 3];
#pragma unroll
            for (int nt = 0; nt < 4; ++nt) {
                const int e = nt * 16 + lr;
                half4_ vh;
                vh[0] = (_Float16)(acc[mt][nt][0] + b0f);
                vh[1] = (_Float16)(acc[mt][nt][1] + b1f);
                vh[2] = (_Float16)(acc[mt][nt][2] + b2f);
                vh[3] = (_Float16)(acc[mt][nt][3] + b3f);
                hJ[(jb + 0) * 72 + e] = vh[0];
                hJ[(jb + 1) * 72 + e] = vh[1];
                hJ[(jb + 2) * 72 + e] = vh[2];
                hJ[(jb + 3) * 72 + e] = vh[3];
                if (wantT) *(half4_*)(hT + e * 72 + jb) = vh;
            }
        }
    };

    // ---- phase 0 ----
    sgemm(R_B, 32, S0);                    // S0 = x @ x^T (B from xJ)
    kloop(Wt0, 32, 0, R_A, 40);            // hT0, full K
    __syncthreads();                       // B1
    epi(bs0, R_A, R_B, true);              // hJ1 -> R_A, hT1 -> R_B
    __syncthreads();                       // B2
    // ---- phase 1 ----
    sgemm(R_A, 64, S1);                    // S1 = x @ h1^T
    kloop(Wt1, 64, 1, R_B, 72);            // hT1, full K
    __syncthreads();                       // B3
    epi(bs1, R_B, nullptr, false);         // hJ2 -> R_B
    __syncthreads();                       // B4
    sgemm(R_B, 64, S2);                    // S2 = x @ h2^T
}

// Direct-output GEMM: out[b, ob+k] = S_l[b,:] . Wt_l[:, dm0+k] + 64*bias.
// 1024 tasks x K-split-2: grid 512, 4 waves = 2 tasks x 2 K-halves.
__global__ __launch_bounds__(256, 2)
void cin_direct(const _Float16* __restrict__ S0v, const _Float16* __restrict__ S1v,
                const _Float16* __restrict__ S2v,
                const _Float16* __restrict__ Wt0, const _Float16* __restrict__ Wt1,
                const _Float16* __restrict__ Wt2,
                const float* __restrict__ bs0, const float* __restrict__ bs1,
                const float* __restrict__ bs2,
                float* __restrict__ out)
{
    __shared__ f32x4 red[2][64];
    const int t = threadIdx.x, lane = t & 63, w = t >> 6;
    const int lr = lane & 15, q = lane >> 4;
    const int task = blockIdx.x * 2 + (w >> 1);
    const int kh = w & 1;

    const _Float16 *S, *Wt;
    const float* bias;
    int fan, nch, dm0, ob, idx;
    if (task < 256)      { S = S0v; Wt = Wt0; bias = bs0; fan = 1024; nch = 32; dm0 = 64; ob = 0;   idx = task; }
    else if (task < 512) { S = S1v; Wt = Wt1; bias = bs1; fan = 2048; nch = 64; dm0 = 64; ob = 64;  idx = task - 256; }
    else                 { S = S2v; Wt = Wt2; bias = bs2; fan = 2048; nch = 64; dm0 = 0;  ob = 128; idx = task - 512; }
    const int bt = idx & 63, kt = idx >> 6;
    const int bbase = bt * 16;
    const int hn = nch >> 1, c0 = kh * hn;

    const _Float16* aG = Wt + (size_t)(dm0 + kt * 16 + lr) * 32 + q * 8
                            + (size_t)c0 * 4096;
    const _Float16* bG = S + (size_t)(bbase + lr) * fan + q * 8 + c0 * 32;

    f32x4 acc = {0.0f, 0.0f, 0.0f, 0.0f};
    half8 aA = *(const half8*)(aG);
    half8 bA = *(const half8*)(bG);
    for (int c = 0; c < hn; c += 2) {
        half8 aB = *(const half8*)(aG + (size_t)(c + 1) * 4096);
        half8 bB = *(const half8*)(bG + (c + 1) * 32);
        acc = __builtin_amdgcn_mfma_f32_16x16x32_f16(aA, bA, acc, 0, 0, 0);
        if (c + 2 < hn) {
            aA = *(const half8*)(aG + (size_t)(c + 2) * 4096);
            bA = *(const half8*)(bG + (c + 2) * 32);
        }
        acc = __builtin_amdgcn_mfma_f32_16x16x32_f16(aB, bB, acc, 0, 0, 0);
    }
    if (kh == 1) red[w >> 1][lane] = acc;
    __syncthreads();
    if (kh == 0) {
        f32x4 o = red[w >> 1][lane];
#pragma unroll
        for (int r = 0; r < 4; ++r) {
            int kl = kt * 16 + q * 4 + r;
            out[(size_t)(bbase + lr) * 256 + ob + kl]
                = acc[r] + o[r] + 64.0f * bias[dm0 + kl];
        }
    }
}

extern "C" void kernel_launch(void* const* d_in, const int* in_sizes, int n_in,
                              void* d_out, int out_size, void* d_ws, size_t ws_size,
                              hipStream_t stream)
{
    const float* x  = (const float*)d_in[0];
    const float* W0 = (const float*)d_in[1];
    const float* b0 = (const float*)d_in[2];
    const float* W1 = (const float*)d_in[3];
    const float* b1 = (const float*)d_in[4];
    const float* W2 = (const float*)d_in[5];
    const float* b2 = (const float*)d_in[6];
    float* out = (float*)d_out;

    char* ws = (char*)d_ws;
    _Float16* Wt0 = (_Float16*)(ws + 0);           // 256 KB
    _Float16* Wt1 = (_Float16*)(ws + 262144);      // 512 KB
    _Float16* Wt2 = (_Float16*)(ws + 786432);      // 512 KB
    _Float16* S0  = (_Float16*)(ws + 1310720);     // 2 MB  (1024 x 1024 f16)
    _Float16* S1  = (_Float16*)(ws + 3407872);     // 4 MB  (1024 x 2048 f16)
    _Float16* S2  = (_Float16*)(ws + 7602176);     // 4 MB
    (void)in_sizes; (void)n_in; (void)out_size; (void)ws_size;

    hipLaunchKernelGGL(pack_w_all, dim3(160), dim3(256), 0, stream,
                       W0, Wt0, W1, Wt1, W2, Wt2);

    hipLaunchKernelGGL(cin_fused, dim3(1024), dim3(128), 0, stream,
                       x, Wt0, Wt1, b0, b1, S0, S1, S2);

    hipLaunchKernelGGL(cin_direct, dim3(512), dim3(256), 0, stream,
                       S0, S1, S2, Wt0, Wt1, Wt2, b0, b1, b2, out);
}